// Round 4
// baseline (243.206 us; speedup 1.0000x reference)
//
#include <hip/hip_runtime.h>
#include <stdint.h>

#define BATCH   32
#define ROWS    4096
#define COLS    256
#define COL_IDX 5

typedef unsigned long long u64;
typedef unsigned int       u32;

// ---------------------------------------------------------------------------
// Kernel 1: extract column COL_IDX, pack into order-preserving u64 keys.
//   hi 32 = ~(order_preserving_uint(f))  -> ascending u64 == descending float
//   lo 32 = row index                    -> distinct keys, stable tie-break
// ---------------------------------------------------------------------------
__global__ __launch_bounds__(256)
void extract_keys_kernel(const float* __restrict__ x, u64* __restrict__ keys) {
    const int i = blockIdx.x * 256 + threadIdx.x;      // 0 .. BATCH*ROWS-1
    u32 u = __float_as_uint(x[(size_t)i * COLS + COL_IDX]);
    u = (u >> 31) ? ~u : (u | 0x80000000u);            // order-preserving map
    u = ~u;                                            // descending
    keys[i] = ((u64)u << 32) | (u32)(i & (ROWS - 1));
}

// ---------------------------------------------------------------------------
// Kernel 2: ballot-rank + async-LDS-staged row copy.
// Block owns 64 consecutive rows (lane l <-> row r0+l).
//
// R3 LESSON: rank and copy phases serialize chip-wide (all blocks aligned) —
// the 128 MiB source read was unoverlapped. Fix: stage the block's 64 rows
// (64 KB) into LDS via global_load_lds (1 KB/instruction, zero VGPR cost —
// avoids R2's register-spill trap) issued BEFORE the rank loop. vmcnt
// decrements in order, so key loads are issued FIRST (their vmcnt(16) wait
// then leaves the 16 DMA ops in flight); sched_barrier(0) pins the order.
// The __syncthreads before the copy drains vmcnt(0) anyway (HIP barrier
// semantics), so staging completion is free. Copy phase is write-only.
// ---------------------------------------------------------------------------
__global__ __launch_bounds__(256, 2)
void rank_copy_kernel(const float* __restrict__ x,
                      const u64* __restrict__ keys,
                      float* __restrict__ out) {
    __shared__ float rows[64 * 256];            // 64 KB row staging
    __shared__ int   part[4][64];               // 1 KB rank partials
    const int w    = (int)threadIdx.x >> 6;     // wave in block (0..3)
    const int lane = (int)threadIdx.x & 63;
    const int b    = blockIdx.x >> 6;           // 64 blocks per batch
    const int r0   = (blockIdx.x & 63) << 6;    // block's first row
    const u64* __restrict__ kb = keys + (size_t)b * ROWS;

    // ---- (1) key loads FIRST: this wave's quarter + its own row key ----
    const int jbeg = w * (ROWS / 4);
    u64 kv[16];
    #pragma unroll
    for (int t = 0; t < 16; ++t)
        kv[t] = kb[jbeg + t * 64 + lane];
    const u64 my = kb[r0 + lane];

    __builtin_amdgcn_sched_barrier(0);          // DMA stays after key loads

    // ---- (2) async DMA: wave w stages rows [w*16, w*16+16) into LDS.
    //      One instruction = 64 lanes x 16 B = one full 1 KB row;
    //      HW writes lds_base + lane*16 (linear), src is per-lane. ----
    const float* __restrict__ xb = x + ((size_t)b * ROWS + r0) * COLS;
    #pragma unroll
    for (int t = 0; t < 16; ++t) {
        const int row = w * 16 + t;
        __builtin_amdgcn_global_load_lds(
            (const __attribute__((address_space(1))) void*)
                (xb + (size_t)row * COLS + lane * 4),
            (__attribute__((address_space(3))) void*)&rows[row * 256],
            16, 0, 0);
    }

    __builtin_amdgcn_sched_barrier(0);          // rank stays after DMA issue

    // ---- (3) ballot rank, overlapped with the in-flight DMA ----
    const u32 my_lo = (u32)my, my_hi = (u32)(my >> 32);
    int vrank = 0;
    #pragma unroll 2
    for (int m = 0; m < 64; ++m) {
        const u32 klo = (u32)__builtin_amdgcn_readlane((int)my_lo, m);
        const u32 khi = (u32)__builtin_amdgcn_readlane((int)my_hi, m);
        const u64 mym = ((u64)khi << 32) | klo;
        int rank_m = 0;
        #pragma unroll
        for (int t = 0; t < 16; ++t)
            rank_m += (int)__popcll(__ballot(kv[t] < mym));
        vrank = (lane == m) ? rank_m : vrank;   // uniform rank_m -> lane m
    }
    part[w][lane] = vrank;

    __syncthreads();    // drains vmcnt(0)+lgkmcnt(0): rows[] complete

    const int total = part[0][lane] + part[1][lane]
                    + part[2][lane] + part[3][lane];

    // ---- (4) write-only copy: LDS row -> 1 KB contiguous HBM store ----
    float4* __restrict__ outb = (float4*)(out + (size_t)b * ROWS * COLS);
    #pragma unroll 4
    for (int t = 0; t < 16; ++t) {
        const int l   = w * 16 + t;
        const int dst = __builtin_amdgcn_readlane(total, l);   // uniform
        const float4 v = ((const float4*)&rows[l * 256])[lane];
        outb[(size_t)dst * 64 + lane] = v;
    }
}

extern "C" void kernel_launch(void* const* d_in, const int* in_sizes, int n_in,
                              void* d_out, int out_size, void* d_ws, size_t ws_size,
                              hipStream_t stream) {
    const float* x   = (const float*)d_in[0];
    float*       out = (float*)d_out;
    u64*         keys = (u64*)d_ws;            // BATCH*ROWS*8 = 1 MB scratch

    extract_keys_kernel<<<(BATCH * ROWS) / 256, 256, 0, stream>>>(x, keys);
    rank_copy_kernel<<<BATCH * 64, 256, 0, stream>>>(x, keys, out);
}